// Round 14
// baseline (369.728 us; speedup 1.0000x reference)
//
#include <hip/hip_runtime.h>

#define L1_BINS 2048          // high 11 bits of 22-bit key
#define L2_SIZE 2048          // low 11 bits
#define KEY_MAX 4194303u      // 2^22 - 1
#define NKEYS 4194304
#define NZ_BLOCKS 2048
#define NH2_BLOCKS 2048
#define NSUM_BLOCKS 2048      // == L1_BINS, one block per L1 bin

struct Ranks { unsigned int r[32]; };
struct Fracs { float f[16]; };

__device__ __forceinline__ unsigned int wave_iscan(unsigned int s, int lane) {
  unsigned int inc = s;
#pragma unroll
  for (int d = 1; d < 64; d <<= 1) {
    unsigned int u = __shfl_up(inc, d);
    if (lane >= d) inc += u;
  }
  return inc;
}

// two-level 64x32 rank-select over 2048 entries; mask16 -> use low 16 bits
__device__ __forceinline__ unsigned int sel2048(const unsigned int* __restrict__ h,
                                                bool mask16, unsigned int rem,
                                                int lane, unsigned int* remOut) {
  unsigned int s = 0;
#pragma unroll 8
  for (int t = 0; t < 32; ++t) {
    unsigned int v = h[lane * 32 + t];
    s += mask16 ? (v & 0xFFFFu) : v;
  }
  unsigned int inc = wave_iscan(s, lane);
  unsigned int ex = inc - s;
  bool own = (rem >= ex) && (rem < ex + s);
  int src = __ffsll((long long)__ballot(own)) - 1;
  rem -= __shfl(ex, src);
  unsigned int v2 = (lane < 32) ? h[src * 32 + lane] : 0u;
  if (mask16) v2 &= 0xFFFFu;
  unsigned int inc2 = wave_iscan(v2, lane);
  unsigned int ex2 = inc2 - v2;
  bool own2 = (lane < 32) && (rem >= ex2) && (rem < ex2 + v2);
  int s2 = __ffsll((long long)__ballot(own2)) - 1;
  *remOut = rem - __shfl(ex2, s2);
  return (unsigned int)(src * 32 + s2);
}

// ---- Kernel 0: zero fullhist (16MB) + done counter -----------------------
__global__ __launch_bounds__(256) void k_zero(uint4* __restrict__ p,
                                              unsigned int* __restrict__ dones) {
  int stride = gridDim.x * blockDim.x;
  int n4 = NKEYS / 4;
  for (int i = blockIdx.x * blockDim.x + threadIdx.x; i < n4; i += stride)
    p[i] = make_uint4(0u, 0u, 0u, 0u);
  if (blockIdx.x == 0 && threadIdx.x < 4) dones[threadIdx.x] = 0u;
}

// ---- Kernel 1: 4 lanes/row coalesced; one global atomic per row ----------
__global__ __launch_bounds__(256) void k_h2(const float4* __restrict__ lg4,
                                            const int* __restrict__ labels,
                                            unsigned int* __restrict__ fullhist,
                                            int n) {
  int tid = blockIdx.x * 256 + threadIdx.x;
  int sub = tid & 3;
  int group = tid >> 2;
  int ngroups = (gridDim.x * 256) >> 2;
  for (int row = group; row < n; row += ngroups) {
    float4 v = lg4[(size_t)row * 4 + sub];
    float m = v.x; int a = 0;
    if (v.y > m) { m = v.y; a = 1; }
    if (v.z > m) { m = v.z; a = 2; }
    if (v.w > m) { m = v.w; a = 3; }
    int gidx = sub * 4 + a;
#pragma unroll
    for (int mask = 1; mask <= 2; mask <<= 1) {
      float om = __shfl_xor(m, mask);
      int oi = __shfl_xor(gidx, mask);
      if (om > m || (om == m && oi < gidx)) { m = om; gidx = oi; }
    }
    float e0 = __expf(v.x - m), e1 = __expf(v.y - m);
    float e2 = __expf(v.z - m), e3 = __expf(v.w - m);
    float Z = e0 + e1 + e2 + e3;
    float S2 = e0 * e0 + e1 * e1 + e2 * e2 + e3 * e3;
#pragma unroll
    for (int mask = 1; mask <= 2; mask <<= 1) {
      Z += __shfl_xor(Z, mask);
      S2 += __shfl_xor(S2, mask);
    }
    if (sub == 0) {
      float r = S2 / (Z * Z) + 1e-12f;
      float h2 = -__log2f(r);
      int ki = (int)(h2 * 1048576.0f);
      unsigned int key = (unsigned int)min(max(ki, 0), (int)KEY_MAX);
      unsigned int er = (gidx != labels[row]) ? 1u : 0u;
      atomicAdd(&fullhist[key], 1u | (er << 16));
    }
  }
}

// ---- Kernel 2: per-L1-bin sums; last block: select + thresholds + FINAL ---
__global__ __launch_bounds__(256) void k_sum(const unsigned int* __restrict__ fullhist,
                                             unsigned int* __restrict__ g_cnt,
                                             unsigned int* __restrict__ g_err,
                                             unsigned long long* __restrict__ g_kk,
                                             unsigned int* __restrict__ dones,
                                             float* __restrict__ out,
                                             Ranks rk, Fracs fr) {
  __shared__ unsigned int wc[4], we2[4];
  __shared__ unsigned long long wk[4];
  __shared__ unsigned int sv[32];
  __shared__ unsigned int sTT[16];
  __shared__ double SCa[16], SEa[16], SKa[16];
  __shared__ double red[3][4];
  __shared__ unsigned int is_last;
  int lane = threadIdx.x & 63;
  int wid = threadIdx.x >> 6;
  // ---- reduce this block's L1 bin ----
  {
    const unsigned int* slice = fullhist + (size_t)blockIdx.x * L2_SIZE;
    unsigned int c = 0, e = 0;
    unsigned long long kk = 0ull;
    for (int t = threadIdx.x; t < L2_SIZE; t += 256) {
      unsigned int w = slice[t];
      unsigned int cc = w & 0xFFFFu;
      c += cc;
      e += w >> 16;
      kk += (unsigned long long)cc * (unsigned long long)t;
    }
    for (int off = 32; off > 0; off >>= 1) {
      c += __shfl_xor(c, off);
      e += __shfl_xor(e, off);
      kk += __shfl_xor(kk, off);
    }
    if (lane == 0) { wc[wid] = c; we2[wid] = e; wk[wid] = kk; }
    __syncthreads();
    if (threadIdx.x == 0) {
      g_cnt[blockIdx.x] = wc[0] + wc[1] + wc[2] + wc[3];
      g_err[blockIdx.x] = we2[0] + we2[1] + we2[2] + we2[3];
      g_kk[blockIdx.x] = wk[0] + wk[1] + wk[2] + wk[3];
    }
  }
  __threadfence();
  __syncthreads();
  if (threadIdx.x == 0)
    is_last = (atomicAdd(&dones[0], 1u) == (unsigned int)gridDim.x - 1u) ? 1u : 0u;
  __syncthreads();
  if (!is_last) return;
  __threadfence();
  // ---- rank selection: 4 waves x 8 queries -> exact 22-bit keys ----
  for (int j = wid; j < 32; j += 4) {
    unsigned int rem;
    unsigned int a = sel2048(g_cnt, false, rk.r[j], lane, &rem);
    unsigned int rem2;
    unsigned int s = sel2048(fullhist + (size_t)a * L2_SIZE, true, rem, lane, &rem2);
    if (lane == 0) sv[j] = (a << 11) | s;
  }
  __syncthreads();
  // ---- edges -> integer thresholds T[j] (f32 math identical to reference) -
  if (threadIdx.x < 16) {
    int i = threadIdx.x;
    float lo = (float)(sv[2 * i] + 1u) * 0x1p-20f;   // exact
    float hi = (float)(sv[2 * i + 1] + 1u) * 0x1p-20f;
    float f = fr.f[i];
    float e = lo * (1.0f - f) + hi * f;
    if (i == 15) e += 1e-6f;
    double kdd = (double)e * 1048576.0 - 0.5;
    int T = (int)floor(kdd) + 1;
    while (T > 0 && ((float)(T - 1) + 0.5f) * 0x1p-20f > e) --T;
    while (((float)T + 0.5f) * 0x1p-20f <= e) ++T;
    sTT[i] = (unsigned int)T;
  }
  __syncthreads();
  // ---- S(T) = sums over keys < T of {cnt, err, keysum} ----
  for (int j = 0; j < 16; ++j) {
    unsigned int T = sTT[j];
    int a1 = (int)(T >> 11);     // 0..2048 full bins
    int r = (int)(T & 2047u);
    double cd = 0.0, ed = 0.0, kd = 0.0;
    for (int i = threadIdx.x; i < a1; i += 256) {
      double c = (double)g_cnt[i];
      cd += c;
      ed += (double)g_err[i];
      kd += (double)((unsigned long long)i << 11) * c + (double)g_kk[i];
    }
    if (a1 < L1_BINS && r > 0) {
      const unsigned int* slice = fullhist + (size_t)a1 * L2_SIZE;
      double base = (double)((unsigned long long)a1 << 11);
      for (int s0 = threadIdx.x; s0 < r; s0 += 256) {
        unsigned int w = slice[s0];
        double c = (double)(w & 0xFFFFu);
        cd += c;
        ed += (double)(w >> 16);
        kd += c * (base + (double)s0);
      }
    }
    for (int off = 32; off > 0; off >>= 1) {
      cd += __shfl_xor(cd, off);
      ed += __shfl_xor(ed, off);
      kd += __shfl_xor(kd, off);
    }
    if (lane == 0) { red[0][wid] = cd; red[1][wid] = ed; red[2][wid] = kd; }
    __syncthreads();
    if (threadIdx.x == 0) {
      SCa[j] = red[0][0] + red[0][1] + red[0][2] + red[0][3];
      SEa[j] = red[1][0] + red[1][1] + red[1][2] + red[1][3];
      SKa[j] = red[2][0] + red[2][1] + red[2][2] + red[2][3];
    }
    __syncthreads();
  }
  if (threadIdx.x == 0) {
    float g = 0.f;
    for (int b = 0; b < 15; ++b) {
      double cd = SCa[b + 1] - SCa[b];
      double ed = SEa[b + 1] - SEa[b];
      double kd = SKa[b + 1] - SKa[b];
      double safe = cd > 1.0 ? cd : 1.0;
      float u = (float)(((kd + 0.5 * cd) * (1.0 / 1048576.0)) / safe);
      float eb = (float)(ed / safe);
      float inner = 2.0f * exp2f(-u) - 1.0f;
      float s = (inner > 0.f) ? sqrtf(inner) : 0.f;
      float risk = 0.5f * (1.0f - s);
      g += (cd > 0.0) ? fabsf(eb - risk) : 0.f;
    }
    out[0] = g * (1.0f / 15.0f);
  }
}

extern "C" void kernel_launch(void* const* d_in, const int* in_sizes, int n_in,
                              void* d_out, int out_size, void* d_ws, size_t ws_size,
                              hipStream_t stream) {
  const float* logits = (const float*)d_in[0];
  const int* labels = (const int*)d_in[1];
  float* out = (float*)d_out;
  int n = in_sizes[1];  // labels count = number of rows

  char* ws = (char*)d_ws;
  size_t offHist = 0;                                  // NKEYS*4 = 16MB
  size_t offGcnt = (size_t)NKEYS * 4;                  // 2048*4
  size_t offGerr = offGcnt + (size_t)L1_BINS * 4;      // 2048*4
  size_t offGkk = offGerr + (size_t)L1_BINS * 4;       // 2048*8 (8B aligned)
  size_t offDone = offGkk + (size_t)L1_BINS * 8;       // 16B

  unsigned int* fullhist = (unsigned int*)(ws + offHist);
  unsigned int* g_cnt = (unsigned int*)(ws + offGcnt);
  unsigned int* g_err = (unsigned int*)(ws + offGerr);
  unsigned long long* g_kk = (unsigned long long*)(ws + offGkk);
  unsigned int* dones = (unsigned int*)(ws + offDone);

  // host-side quantile positions (f32, matching jnp.linspace/quantile math)
  Ranks rk;
  Fracs fr;
  float nm1 = (float)(n - 1);
  for (int i = 0; i < 16; ++i) {
    float q = (i == 15) ? 1.0f : (float)i * (1.0f / 15.0f);
    float idxf = q * nm1;
    float flo = floorf(idxf);
    unsigned int klo = (unsigned int)flo;
    unsigned int khi = (unsigned int)ceilf(idxf);
    unsigned int maxi = (unsigned int)(n - 1);
    if (klo > maxi) klo = maxi;
    if (khi > maxi) khi = maxi;
    rk.r[2 * i] = klo;
    rk.r[2 * i + 1] = khi;
    fr.f[i] = idxf - flo;
  }

  // 0) zero full histogram + done counter
  k_zero<<<NZ_BLOCKS, 256, 0, stream>>>((uint4*)fullhist, dones);
  // 1) H2 keys -> one global atomic per row (no LDS, no keys array)
  k_h2<<<NH2_BLOCKS, 256, 0, stream>>>((const float4*)logits, labels, fullhist, n);
  // 2) per-bin sums; last block: rank select + thresholds + range sums + out
  k_sum<<<NSUM_BLOCKS, 256, 0, stream>>>(fullhist, g_cnt, g_err, g_kk, dones, out, rk, fr);

  (void)n_in; (void)out_size; (void)ws_size;
}